// Round 1
// baseline (255.744 us; speedup 1.0000x reference)
//
#include <hip/hip_runtime.h>
#include <math.h>

// Per-position head-vs-head attention (Hilbert perm cancels; see R0 notes).
// R2: persistent waves + software pipeline. R1 was latency-bound: 16 waves/SIMD
// lifetime ~51k cy for ~2k cy of work (burst-load, stall, exit, relaunch).
// Now each wave owns TPW positions; loads for t+1 issue into registers while
// t computes from LDS (counted-vmcnt overlap, zero barriers still). Output
// uses non-temporal stores so the 67 MB output stream doesn't thrash the
// 256 MB L3 that serves ~half the input reads.

#define HEADS 16
#define DIM 64
// LDS per tensor slice: grp0 512 floats, +4 pad, grp1 512 floats.
// Pad keeps the 8-distinct-address b128 reads at 2-per-bank-span (free, m136).
#define GSTRIDE 516
#define TSLICE  (2 * GSTRIDE)      // 1032 floats per tensor (k or v)
#define WSLICE  (2 * TSLICE)       // 2064 floats per wave slice
#define WPB 4                      // waves per block
#define TPW 4                      // positions per wave (grid-stride)

typedef float f32x4 __attribute__((ext_vector_type(4)));

__device__ __forceinline__ void issue_loads(
    const float* __restrict__ q, const float* __restrict__ k,
    const float* __restrict__ v, long long gbase, int lane,
    f32x4* qr, f32x4* ks, f32x4* vs)
{
    const int i = lane >> 2;          // head 0..15
    const int s = lane & 3;           // 16-float sub-chunk of dim
    const float* qp = q + gbase + i * DIM + s * 16;
    qr[0] = *(const f32x4*)(qp + 0);
    qr[1] = *(const f32x4*)(qp + 4);
    qr[2] = *(const f32x4*)(qp + 8);
    qr[3] = *(const f32x4*)(qp + 12);
#pragma unroll
    for (int it = 0; it < 4; ++it) {
        const int sfo = it * 256 + lane * 4;     // coalesced 1KB per instr
        ks[it] = *(const f32x4*)(k + gbase + sfo);
        vs[it] = *(const f32x4*)(v + gbase + sfo);
    }
}

__device__ __forceinline__ void stage_to_lds(
    float* kk, float* vv, int lane, const f32x4* ks, const f32x4* vs)
{
#pragma unroll
    for (int it = 0; it < 4; ++it) {
        const int dfo = it * 256 + lane * 4 + ((it >= 2) ? 4 : 0); // +pad grp1
        *(f32x4*)(kk + dfo) = ks[it];
        *(f32x4*)(vv + dfo) = vs[it];
    }
}

__device__ __forceinline__ void compute_store(
    const float* kk, const float* vv, int lane, const f32x4* qr,
    float* __restrict__ outp)
{
    const int i   = lane >> 2;
    const int s   = lane & 3;
    const int grp = i >> 3;

    // ---- Phase A: partial scores over this lane's 16 dims, all 8 j.
    const float* kg = kk + grp * GSTRIDE;
    float sc[8];
#pragma unroll
    for (int j = 0; j < 8; ++j) {
        const float* kr = kg + j * DIM + s * 16;
        f32x4 p = qr[0] * *(const f32x4*)(kr + 0)
                + qr[1] * *(const f32x4*)(kr + 4)
                + qr[2] * *(const f32x4*)(kr + 8)
                + qr[3] * *(const f32x4*)(kr + 12);
        sc[j] = p.x + p.y + p.z + p.w;
    }
    // Complete dots across the 4 s-lanes (lanes i*4+s contiguous).
#pragma unroll
    for (int j = 0; j < 8; ++j) {
        sc[j] += __shfl_xor(sc[j], 1);
        sc[j] += __shfl_xor(sc[j], 2);
        sc[j] *= 0.125f;              // HEAD_DIM^-0.5
    }

    // ---- Softmax fully in-lane.
    float m = sc[0];
#pragma unroll
    for (int j = 1; j < 8; ++j) m = fmaxf(m, sc[j]);
    float at[8];
    float sum = 0.f;
#pragma unroll
    for (int j = 0; j < 8; ++j) { at[j] = __expf(sc[j] - m); sum += at[j]; }
    const float inv = 1.f / sum;
#pragma unroll
    for (int j = 0; j < 8; ++j) at[j] *= inv;

    // ---- Phase B: out[i][s*16..) = sum_j at[j] * v[g*8+j][chunk s]
    const float* vg = vv + grp * GSTRIDE;
    f32x4 o0 = {0.f, 0.f, 0.f, 0.f};
    f32x4 o1 = o0, o2 = o0, o3 = o0;
#pragma unroll
    for (int j = 0; j < 8; ++j) {
        const float a = at[j];
        const float* vr = vg + j * DIM + s * 16;
        o0 += a * *(const f32x4*)(vr + 0);
        o1 += a * *(const f32x4*)(vr + 4);
        o2 += a * *(const f32x4*)(vr + 8);
        o3 += a * *(const f32x4*)(vr + 12);
    }

    // ---- Non-temporal 64B store per lane (don't pollute L3 with output).
    float* op = outp + i * DIM + s * 16;
    __builtin_nontemporal_store(o0, (f32x4*)(op + 0));
    __builtin_nontemporal_store(o1, (f32x4*)(op + 4));
    __builtin_nontemporal_store(o2, (f32x4*)(op + 8));
    __builtin_nontemporal_store(o3, (f32x4*)(op + 12));
}

__global__ void __launch_bounds__(256, 4) hilbert_attn_kernel(
    const float* __restrict__ q,
    const float* __restrict__ k,
    const float* __restrict__ v,
    float* __restrict__ out,
    int npos)
{
    __shared__ float lds[WPB * WSLICE];   // 33,024 B -> 4 blocks/CU
    const int wave = threadIdx.x >> 6;
    const int lane = threadIdx.x & 63;
    const long long nw = (long long)gridDim.x * WPB;

    long long t0 = (long long)blockIdx.x * WPB + wave;
    if (t0 >= npos) return;               // wave-uniform

    float* kk = lds + wave * WSLICE;      // wave-private slice: no barriers
    float* vv = kk + TSLICE;

    f32x4 qA[4], kA[4], vA[4];
    f32x4 qB[4], kB[4], vB[4];

    issue_loads(q, k, v, t0 * (HEADS * DIM), lane, qA, kA, vA);

    for (;;) {
        // Issue next position's loads BEFORE consuming current: HBM latency
        // hides under stage+compute (~2k cy). All branch conds wave-uniform.
        const long long t1 = t0 + nw;
        if (t1 < npos) issue_loads(q, k, v, t1 * (HEADS * DIM), lane, qB, kB, vB);
        stage_to_lds(kk, vv, lane, kA, vA);        // waits only on A's loads
        compute_store(kk, vv, lane, qA, out + t0 * (HEADS * DIM));
        if (t1 >= npos) return;

        const long long t2 = t1 + nw;
        if (t2 < npos) issue_loads(q, k, v, t2 * (HEADS * DIM), lane, qA, kA, vA);
        stage_to_lds(kk, vv, lane, kB, vB);
        compute_store(kk, vv, lane, qB, out + t1 * (HEADS * DIM));
        if (t2 >= npos) return;
        t0 = t2;
    }
}

extern "C" void kernel_launch(void* const* d_in, const int* in_sizes, int n_in,
                              void* d_out, int out_size, void* d_ws, size_t ws_size,
                              hipStream_t stream) {
    const float* q = (const float*)d_in[0];
    const float* k = (const float*)d_in[1];
    const float* v = (const float*)d_in[2];
    float* out = (float*)d_out;

    const int npos = in_sizes[0] / (HEADS * DIM);   // B*S = 16384
    const int blocks = (npos + WPB * TPW - 1) / (WPB * TPW);  // 1024: 4/CU resident
    hilbert_attn_kernel<<<blocks, WPB * 64, 0, stream>>>(q, k, v, out, npos);
}

// Round 2
// 211.600 us; speedup vs baseline: 1.2086x; 1.2086x over previous
//
#include <hip/hip_runtime.h>
#include <math.h>

// Per-position head-vs-head attention (Hilbert perm cancels; see R0 notes).
// R3: occupancy doubling. R2 post-mortem: nt stores caused 2.4x write
// amplification (partial-line HBM RMW) -- reverted; per-wave pipeline added
// no MLP (VALUBusy fell to 5%) -- reverted. R1 was TLP-bound at 16 waves/CU
// (LDS 33KB/block -> 4 blocks/CU). Fix: split each position across 2 waves,
// one per head-group (groups are independent 8x8 attention problems; each
// group's k/v is a contiguous 2KB). Per-wave LDS 8.25KB -> 4KB exact, block
// 16KB -> 8 blocks/CU -> 32 waves/CU (HW max). Zero barriers still.
// No pad needed: 8-float-chunk reads are <=2-way bank aliasing (free, m136).

#define HEADS 16
#define DIM 64
#define GH 8                      // heads per group
#define GFLOATS (GH * DIM)        // 512 floats: one group of one tensor
#define WSLICE (2 * GFLOATS)      // k + v slice per wave = 1024 floats = 4KB
#define WPB 4                     // waves per block

typedef float f32x4 __attribute__((ext_vector_type(4)));

__global__ void __launch_bounds__(256, 8) hilbert_attn_kernel(
    const float* __restrict__ q,
    const float* __restrict__ k,
    const float* __restrict__ v,
    float* __restrict__ out,
    int npos)
{
    __shared__ float lds[WPB * WSLICE];   // 16,384 B -> 8 blocks/CU
    const int wave = threadIdx.x >> 6;
    const int lane = threadIdx.x & 63;

    const long long w   = (long long)blockIdx.x * WPB + wave; // global wave id
    const long long pos = w >> 1;
    const int       grp = (int)(w & 1);
    if (pos >= npos) return;              // wave-uniform; no barriers below

    float* kk = lds + wave * WSLICE;      // wave-private: no __syncthreads
    float* vv = kk + GFLOATS;

    // Group g of position p is a contiguous 512-float block in [H][D] layout.
    const long long gbase = pos * (HEADS * DIM) + (long long)grp * GFLOATS;

    const int i = lane >> 3;              // head within group (0..7)
    const int s = lane & 7;               // 8-float dim chunk (0..7)

    // ---- q sub-row: lane-private 8 floats, issued with the k/v burst.
    const float* qp = q + gbase + i * DIM + s * 8;
    f32x4 q0 = *(const f32x4*)(qp + 0);
    f32x4 q1 = *(const f32x4*)(qp + 4);

    // ---- Stage this group's k,v (2KB each): 2 coalesced 1KB rounds/tensor.
#pragma unroll
    for (int r = 0; r < 2; ++r) {
        const int fo = r * 256 + lane * 4;
        f32x4 a = *(const f32x4*)(k + gbase + fo);
        f32x4 b = *(const f32x4*)(v + gbase + fo);
        *(f32x4*)(kk + fo) = a;
        *(f32x4*)(vv + fo) = b;
    }
    // Compiler inserts vm/lgkm waits; ds_write->ds_read same-wave ordered.

    // ---- Phase A: partial scores over this lane's 8 dims, all 8 j.
    float sc[8];
#pragma unroll
    for (int j = 0; j < 8; ++j) {
        const float* kr = kk + j * DIM + s * 8;
        f32x4 p = q0 * *(const f32x4*)(kr + 0)
                + q1 * *(const f32x4*)(kr + 4);
        sc[j] = p.x + p.y + p.z + p.w;
    }
    // Complete dots across the 8 s-lanes (lane = i*8+s; bits 0..2 are s).
#pragma unroll
    for (int j = 0; j < 8; ++j) {
        sc[j] += __shfl_xor(sc[j], 1);
        sc[j] += __shfl_xor(sc[j], 2);
        sc[j] += __shfl_xor(sc[j], 4);
        sc[j] *= 0.125f;                  // HEAD_DIM^-0.5
    }

    // ---- Softmax fully in-lane (every s-lane holds the full score row).
    float m = sc[0];
#pragma unroll
    for (int j = 1; j < 8; ++j) m = fmaxf(m, sc[j]);
    float at[8];
    float sum = 0.f;
#pragma unroll
    for (int j = 0; j < 8; ++j) { at[j] = __expf(sc[j] - m); sum += at[j]; }
    const float inv = 1.f / sum;
#pragma unroll
    for (int j = 0; j < 8; ++j) at[j] *= inv;

    // ---- Phase B: out[i][s*8..s*8+8) = sum_j at[j] * v[j][chunk s]
    f32x4 o0 = {0.f, 0.f, 0.f, 0.f};
    f32x4 o1 = o0;
#pragma unroll
    for (int j = 0; j < 8; ++j) {
        const float a = at[j];
        const float* vr = vv + j * DIM + s * 8;
        o0 += a * *(const f32x4*)(vr + 0);
        o1 += a * *(const f32x4*)(vr + 4);
    }

    // ---- Plain stores (R2 lesson: nt stores -> 2.4x HBM write amplification).
    float* op = out + gbase + i * DIM + s * 8;
    *(f32x4*)(op + 0) = o0;
    *(f32x4*)(op + 4) = o1;
}

extern "C" void kernel_launch(void* const* d_in, const int* in_sizes, int n_in,
                              void* d_out, int out_size, void* d_ws, size_t ws_size,
                              hipStream_t stream) {
    const float* q = (const float*)d_in[0];
    const float* k = (const float*)d_in[1];
    const float* v = (const float*)d_in[2];
    float* out = (float*)d_out;

    const int npos = in_sizes[0] / (HEADS * DIM);   // B*S = 16384
    const long long nwaves = 2LL * npos;            // 2 group-waves per position
    const int blocks = (int)((nwaves + WPB - 1) / WPB);   // 8192
    hilbert_attn_kernel<<<blocks, WPB * 64, 0, stream>>>(q, k, v, out, npos);
}